// Round 4
// baseline (1499.081 us; speedup 1.0000x reference)
//
#include <hip/hip_runtime.h>

#define HDIM 256
#define EPSV 1e-5f
#define SLOPEV 0.01f

typedef __bf16 bf16;
typedef bf16  bf16x8 __attribute__((ext_vector_type(8)));
typedef bf16  bf16x4 __attribute__((ext_vector_type(4)));
typedef float f32x4  __attribute__((ext_vector_type(4)));

#define GLD16(g, l) __builtin_amdgcn_global_load_lds( \
    (const __attribute__((address_space(1))) void*)(g), \
    (__attribute__((address_space(3))) void*)(l), 16, 0, 0)

// ============ MFMA GEMM: 128x64 tile, 64x32/wave, 4 blocks/CU ============
// out = concat_k(A0..A_{nseg-1}) * Wt^T + bias (+addb residual).
// Occupancy-first design (r1-r3 post-mortems: perf tracked resident waves,
// never pipeline depth): acc halved to 32 AGPR -> ~<=128 regs/wave with
// __launch_bounds__(256,4) -> 4 blocks/CU x 4 waves = 16 waves/CU (was 12).
// LDS 24KB: A [2][128][32]bf16 @0, B [2][64][32]bf16 @16384.
// K-loop = round-1's proven structure (issue-early stage + __syncthreads;
// no hand vmcnt - m131/m141: it regresses under this compiler).
// Epilogue: wave-private staging (stride 40 bf16, aligned b128 reads),
// no barriers (same-wave DS is in-order). STATS templated out when unused.
template<bool STORE_BF16, bool STATS>
__global__ __launch_bounds__(256, 4)
void gemm_bt_k(const bf16* A0, const bf16* A1, const bf16* A2, const bf16* A3,
               int nseg, int segK,
               const bf16* __restrict__ Wt,
               const float* __restrict__ bias, const bf16* __restrict__ addb,
               void* out0, void* out1, void* out2, void* out3, int ldo,
               int n_store, float* part, int n_stats)
{
    __shared__ char smem[24576];

    const int tid = threadIdx.x;
    const int wave = tid >> 6, lane = tid & 63;
    const int quad = lane >> 4, l16 = lane & 15;
    const int waveM = (wave >> 1) * 64, waveN = (wave & 1) * 32;

    // T1: XCD-aware swizzle (all grids here have nwg % 8 == 0; guard anyway).
    int bid = blockIdx.y * gridDim.x + blockIdx.x;
    const int nwg = gridDim.x * gridDim.y;
    if ((nwg & 7) == 0) {
        const int cpx = nwg >> 3;
        bid = (bid & 7) * cpx + (bid >> 3);
    }
    const int bx = bid % gridDim.x, by = bid / gridDim.x;
    const int bm = by * 128, bn = bx * 64;
    const int K = nseg * segK;

    const bf16* segs[4] = {A0, A1, A2, A3};
    const int srow = tid >> 2;            // 0..63
    const int skof = (tid & 3) * 8;       // 0,8,16,24 (bf16 elems)

    f32x4 acc[4][2] = {};

    const int T = K >> 5;                 // K-steps of 32

    auto stage = [&](int s, int kt, int b) {
        const bf16* gA = segs[s] + (size_t)(bm + srow) * segK + kt + skof;
        const bf16* gB = Wt + (size_t)(bn + srow) * K + s * segK + kt + skof;
        char* lA = smem + b * 8192 + wave * 1024;
        char* lB = smem + 16384 + b * 4096 + wave * 1024;
        GLD16(gA,                     lA);          // rows 0..63
        GLD16(gA + (size_t)64 * segK, lA + 4096);   // rows 64..127
        GLD16(gB,                     lB);          // cols 0..63
    };

    stage(0, 0, 0);
    __syncthreads();

    int s = 0, kt = 0;
    for (int t = 0; t < T; ++t) {
        int s2 = s, kt2 = kt + 32;
        if (kt2 == segK) { s2++; kt2 = 0; }
        if (t + 1 < T) stage(s2, kt2, (t + 1) & 1);   // issue-early prefetch

        const bf16* pa = (const bf16*)(smem + (t & 1) * 8192)
                         + (waveM + l16) * 32 + quad * 8;
        const bf16* pb = (const bf16*)(smem + 16384 + (t & 1) * 4096)
                         + (waveN + l16) * 32 + quad * 8;
        bf16x8 a0 = *(const bf16x8*)(pa);
        bf16x8 a1 = *(const bf16x8*)(pa + 16 * 32);
        bf16x8 a2 = *(const bf16x8*)(pa + 32 * 32);
        bf16x8 a3 = *(const bf16x8*)(pa + 48 * 32);
        bf16x8 b0 = *(const bf16x8*)(pb);
        bf16x8 b1 = *(const bf16x8*)(pb + 16 * 32);

        acc[0][0] = __builtin_amdgcn_mfma_f32_16x16x32_bf16(a0, b0, acc[0][0], 0, 0, 0);
        acc[0][1] = __builtin_amdgcn_mfma_f32_16x16x32_bf16(a0, b1, acc[0][1], 0, 0, 0);
        acc[1][0] = __builtin_amdgcn_mfma_f32_16x16x32_bf16(a1, b0, acc[1][0], 0, 0, 0);
        acc[1][1] = __builtin_amdgcn_mfma_f32_16x16x32_bf16(a1, b1, acc[1][1], 0, 0, 0);
        acc[2][0] = __builtin_amdgcn_mfma_f32_16x16x32_bf16(a2, b0, acc[2][0], 0, 0, 0);
        acc[2][1] = __builtin_amdgcn_mfma_f32_16x16x32_bf16(a2, b1, acc[2][1], 0, 0, 0);
        acc[3][0] = __builtin_amdgcn_mfma_f32_16x16x32_bf16(a3, b0, acc[3][0], 0, 0, 0);
        acc[3][1] = __builtin_amdgcn_mfma_f32_16x16x32_bf16(a3, b1, acc[3][1], 0, 0, 0);

        __syncthreads();
        s = s2; kt = kt2;
    }

    float bv[2];
#pragma unroll
    for (int j = 0; j < 2; ++j)
        bv[j] = bias ? bias[bn + waveN + j * 16 + l16] : 0.f;
#pragma unroll
    for (int i = 0; i < 4; ++i)
#pragma unroll
        for (int j = 0; j < 2; ++j)
#pragma unroll
            for (int r = 0; r < 4; ++r)
                acc[i][j][r] += bv[j];

    void* outs[4] = {out0, out1, out2, out3};

    if (STORE_BF16) {
        // wave-private 32x32 staging tile, row stride 40 bf16 (80B, 16B-mult)
        char* stg = smem + wave * 2560;
        float s8[8] = {}, q8[8] = {};
        const int rsel = lane >> 2, csel = lane & 3;
#pragma unroll
        for (int ih = 0; ih < 2; ++ih) {
#pragma unroll
            for (int iw = 0; iw < 2; ++iw) {
                int i = ih * 2 + iw;
#pragma unroll
                for (int j = 0; j < 2; ++j)
#pragma unroll
                    for (int r = 0; r < 4; ++r)
                        *(bf16*)(stg + ((iw * 16 + quad * 4 + r) * 40 + j * 16 + l16) * 2)
                            = (bf16)acc[i][j][r];
            }
            // same-wave DS ops are in-order: reads below see all writes above
#pragma unroll
            for (int rr = 0; rr < 2; ++rr) {
                int rl = rsel + rr * 16;
                bf16x8 v = *(const bf16x8*)(stg + (rl * 40 + csel * 8) * 2);
                int rowg = bm + waveM + ih * 32 + rl;
                int colg = bn + waveN + csel * 8;
                int cseg = colg >> 8, cloc = colg & 255;
                size_t idx = (size_t)rowg * ldo + cloc;
                float f[8];
#pragma unroll
                for (int u = 0; u < 8; ++u) f[u] = (float)v[u];
                if (addb) {
                    bf16x8 o = *(const bf16x8*)(addb + idx);
#pragma unroll
                    for (int u = 0; u < 8; ++u) f[u] += (float)o[u];
                }
                bf16x8 w;
#pragma unroll
                for (int u = 0; u < 8; ++u) w[u] = (bf16)f[u];
                if (rowg < n_store) *(bf16x8*)((bf16*)outs[cseg] + idx) = w;
                if (STATS && rowg < n_stats) {
#pragma unroll
                    for (int u = 0; u < 8; ++u) { s8[u] += f[u]; q8[u] += f[u] * f[u]; }
                }
            }
        }
        if (STATS) {
            // reduce over rsel (lanes differing in bits 2..5)
#pragma unroll
            for (int m = 4; m <= 32; m <<= 1)
#pragma unroll
                for (int u = 0; u < 8; ++u) {
                    s8[u] += __shfl_xor(s8[u], m, 64);
                    q8[u] += __shfl_xor(q8[u], m, 64);
                }
            float* Ls = (float*)(smem + 12288);   // [4][32]
            float* Lq = Ls + 128;                 // [4][32]
            if (rsel == 0) {
#pragma unroll
                for (int u = 0; u < 8; ++u) {
                    Ls[wave * 32 + csel * 8 + u] = s8[u];
                    Lq[wave * 32 + csel * 8 + u] = q8[u];
                }
            }
            __syncthreads();
            if (tid < 64) {
                int wa = tid >> 5, c5 = tid & 31;
                float sv = Ls[wa * 32 + c5] + Ls[(wa + 2) * 32 + c5];
                float qv = Lq[wa * 32 + c5] + Lq[(wa + 2) * 32 + c5];
                int Mtot = gridDim.x * 64;
                int colg = bn + tid;
                part[(size_t)by * Mtot + colg] = sv;
                part[(size_t)(gridDim.y + by) * Mtot + colg] = qv;
            }
        }
    } else {
#pragma unroll
        for (int i = 0; i < 4; ++i)
#pragma unroll
            for (int j = 0; j < 2; ++j) {
                int colg = bn + waveN + j * 16 + l16;
                int cseg = colg >> 8, cloc = colg & 255;
#pragma unroll
                for (int r = 0; r < 4; ++r) {
                    int rowg = bm + waveM + i * 16 + quad * 4 + r;
                    if (rowg < n_store)
                        ((float*)outs[cseg])[(size_t)rowg * ldo + cloc] = acc[i][j][r];
                }
            }
    }
}

// ================= finalize: one block per column, tree reduce =================
__global__ __launch_bounds__(256)
void finalize_k(const float* __restrict__ part, int GY, int M,
                const float* __restrict__ g, const float* __restrict__ bb,
                float* __restrict__ coef, float invn)
{
    const int c = blockIdx.x;
    const int t = threadIdx.x;
    float s = 0.f, q = 0.f;
    const float* ps = part + c;
    const float* pq = part + (size_t)GY * M + c;
    for (int i = t; i < GY; i += 256) {
        s += ps[(size_t)i * M];
        q += pq[(size_t)i * M];
    }
#pragma unroll
    for (int m = 1; m <= 32; m <<= 1) {
        s += __shfl_xor(s, m, 64);
        q += __shfl_xor(q, m, 64);
    }
    __shared__ float Ls[4], Lq[4];
    const int w = t >> 6, l = t & 63;
    if (l == 0) { Ls[w] = s; Lq[w] = q; }
    __syncthreads();
    if (t == 0) {
        s = Ls[0] + Ls[1] + Ls[2] + Ls[3];
        q = Lq[0] + Lq[1] + Lq[2] + Lq[3];
        float mean = s * invn;
        float var  = q * invn - mean * mean;
        float a = g[c] * rsqrtf(var + EPSV);
        coef[c]     = a;
        coef[M + c] = bb[c] - mean * a;
    }
}

// ================= transpose+convert =================
__global__ __launch_bounds__(256)
void transpose_cvt_k(const float* __restrict__ src, bf16* __restrict__ dst,
                     int Kseg, int M, int G)
{
    __shared__ float t[32][33];
    const int z = blockIdx.z;
    src += (size_t)z * Kseg * M;
    const int ldd = G * Kseg;
    dst += (size_t)(z / G) * M * ldd + (size_t)(z % G) * Kseg;
    const int tM = blockIdx.x * 32, tK = blockIdx.y * 32;
    const int tx = threadIdx.x & 31, ty = threadIdx.x >> 5;
#pragma unroll
    for (int r = 0; r < 4; ++r)
        t[ty + r * 8][tx] = src[(size_t)(tK + ty + r * 8) * M + tM + tx];
    __syncthreads();
#pragma unroll
    for (int r = 0; r < 4; ++r)
        dst[(size_t)(tM + ty + r * 8) * ldd + tK + tx] = (bf16)t[tx][ty + r * 8];
}

__global__ __launch_bounds__(256)
void cvt_bf_k(const float* __restrict__ src, bf16* __restrict__ dst, long n4)
{
    long i = (long)blockIdx.x * blockDim.x + threadIdx.x;
    if (i >= n4) return;
    float4 v = ((const float4*)src)[i];
    bf16x4 o; o[0] = (bf16)v.x; o[1] = (bf16)v.y; o[2] = (bf16)v.z; o[3] = (bf16)v.w;
    ((bf16x4*)dst)[i] = o;
}

// ================= CSR build (parallel scan) =================
__global__ __launch_bounds__(256)
void deg_k(const int* __restrict__ dst, int* __restrict__ deg, int E)
{
    int e = blockIdx.x * blockDim.x + threadIdx.x;
    if (e < E) atomicAdd(&deg[dst[e]], 1);
}

__global__ __launch_bounds__(256)
void blocksum_k(const int* __restrict__ deg, int* __restrict__ bsum, int N)
{
    int i = blockIdx.x * 256 + threadIdx.x;
    int v = (i < N) ? deg[i] : 0;
#pragma unroll
    for (int m = 1; m <= 32; m <<= 1) v += __shfl_xor(v, m, 64);
    __shared__ int Ls[4];
    if ((threadIdx.x & 63) == 0) Ls[threadIdx.x >> 6] = v;
    __syncthreads();
    if (threadIdx.x == 0) bsum[blockIdx.x] = Ls[0] + Ls[1] + Ls[2] + Ls[3];
}

__global__ __launch_bounds__(256)
void topscan_k(const int* __restrict__ bsum, int* __restrict__ boff, int nb)
{
    __shared__ int s[256];
    int t = threadIdx.x;
    int v = (t < nb) ? bsum[t] : 0;
    s[t] = v;
    __syncthreads();
    for (int off = 1; off < 256; off <<= 1) {
        int u = (t >= off) ? s[t - off] : 0;
        __syncthreads();
        s[t] += u;
        __syncthreads();
    }
    if (t < nb) boff[t] = s[t] - v;   // exclusive
}

__global__ __launch_bounds__(256)
void scatterscan_k(int* __restrict__ deg_wp, const int* __restrict__ boff,
                   int* __restrict__ rowptr, int N)
{
    __shared__ int s[256];
    int t = threadIdx.x;
    int i = blockIdx.x * 256 + t;
    int v = (i < N) ? deg_wp[i] : 0;
    s[t] = v;
    __syncthreads();
    for (int off = 1; off < 256; off <<= 1) {
        int u = (t >= off) ? s[t - off] : 0;
        __syncthreads();
        s[t] += u;
        __syncthreads();
    }
    if (i < N) {
        int incl = s[t] + boff[blockIdx.x];
        rowptr[i + 1] = incl;
        deg_wp[i] = incl - v;     // exclusive -> reorder write ptr
        if (i == 0) rowptr[0] = 0;
    }
}

__global__ __launch_bounds__(256)
void reorder_k(const int* __restrict__ src, const int* __restrict__ dst,
               const float* __restrict__ ew, int* __restrict__ wp,
               int* __restrict__ col, float* __restrict__ wgt, int E)
{
    int e = blockIdx.x * blockDim.x + threadIdx.x;
    if (e >= E) return;
    int d = dst[e];
    int pos = atomicAdd(&wp[d], 1);
    col[pos] = src[e];
    wgt[pos] = ew[e];
}

// ================= pull SpMM: half-wave (32 lanes x bf16x8) per node =========
// 4-edge unroll: 4 gather loads in flight per half-wave (MLP for the
// L2/L3-latency-bound random row gathers).
__global__ __launch_bounds__(256)
void spmm_pull_k(const bf16* __restrict__ P, const int* __restrict__ rowptr,
                 const int* __restrict__ col, const float* __restrict__ wgt,
                 bf16* __restrict__ Q, int N)
{
    int node = blockIdx.x * 8 + (threadIdx.x >> 5);
    int l = threadIdx.x & 31;
    if (node >= N) return;
    int e = rowptr[node], end = rowptr[node + 1];
    float acc[8] = {};
    for (; e + 3 < end; e += 4) {
        int   s0 = col[e],     s1 = col[e + 1], s2 = col[e + 2], s3 = col[e + 3];
        float w0 = wgt[e],     w1 = wgt[e + 1], w2 = wgt[e + 2], w3 = wgt[e + 3];
        bf16x8 v0 = *(const bf16x8*)(P + (size_t)s0 * HDIM + l * 8);
        bf16x8 v1 = *(const bf16x8*)(P + (size_t)s1 * HDIM + l * 8);
        bf16x8 v2 = *(const bf16x8*)(P + (size_t)s2 * HDIM + l * 8);
        bf16x8 v3 = *(const bf16x8*)(P + (size_t)s3 * HDIM + l * 8);
#pragma unroll
        for (int u = 0; u < 8; ++u)
            acc[u] += ((float)v0[u] * w0 + (float)v1[u] * w1)
                    + ((float)v2[u] * w2 + (float)v3[u] * w3);
    }
    for (; e + 1 < end; e += 2) {
        int   s0 = col[e], s1 = col[e + 1];
        float w0 = wgt[e], w1 = wgt[e + 1];
        bf16x8 v0 = *(const bf16x8*)(P + (size_t)s0 * HDIM + l * 8);
        bf16x8 v1 = *(const bf16x8*)(P + (size_t)s1 * HDIM + l * 8);
#pragma unroll
        for (int u = 0; u < 8; ++u)
            acc[u] += (float)v0[u] * w0 + (float)v1[u] * w1;
    }
    if (e < end) {
        int s0 = col[e]; float w0 = wgt[e];
        bf16x8 v0 = *(const bf16x8*)(P + (size_t)s0 * HDIM + l * 8);
#pragma unroll
        for (int u = 0; u < 8; ++u) acc[u] += (float)v0[u] * w0;
    }
    bf16x8 o;
#pragma unroll
    for (int u = 0; u < 8; ++u) o[u] = (bf16)acc[u];
    *(bf16x8*)(Q + (size_t)node * HDIM + l * 8) = o;
}

// ================= BN apply (coeffs precomputed) =================
__global__ __launch_bounds__(256)
void apply_bn_k(const bf16* __restrict__ X, const float* __restrict__ coef,
                bf16* __restrict__ Y, int n)
{
    __shared__ float aL[256], bL[256];
    const int tid = threadIdx.x;
    aL[tid] = coef[tid]; bL[tid] = coef[256 + tid];
    __syncthreads();
    long n4 = (long)n * 64;
    for (long i = (long)blockIdx.x * 256 + tid; i < n4; i += (long)gridDim.x * 256) {
        bf16x4 v = ((const bf16x4*)X)[i];
        int c4 = (int)(i & 63) * 4;
        float r0 = fmaf((float)v[0], aL[c4 + 0], bL[c4 + 0]); r0 = r0 > 0.f ? r0 : SLOPEV * r0;
        float r1 = fmaf((float)v[1], aL[c4 + 1], bL[c4 + 1]); r1 = r1 > 0.f ? r1 : SLOPEV * r1;
        float r2 = fmaf((float)v[2], aL[c4 + 2], bL[c4 + 2]); r2 = r2 > 0.f ? r2 : SLOPEV * r2;
        float r3 = fmaf((float)v[3], aL[c4 + 3], bL[c4 + 3]); r3 = r3 > 0.f ? r3 : SLOPEV * r3;
        bf16x4 o; o[0] = (bf16)r0; o[1] = (bf16)r1; o[2] = (bf16)r2; o[3] = (bf16)r3;
        ((bf16x4*)Y)[i] = o;
    }
}

__global__ __launch_bounds__(256)
void apply_bn4_k(bf16* X0, bf16* X1, bf16* X2, bf16* X3,
                 const float* __restrict__ coef, int n)
{
    __shared__ float aL[1024], bL[1024];
    const int tid = threadIdx.x;
#pragma unroll
    for (int q = 0; q < 4; ++q) {
        int c = q * 256 + tid;
        aL[c] = coef[c]; bL[c] = coef[1024 + c];
    }
    __syncthreads();
    bf16* Xs[4] = {X0, X1, X2, X3};
    long per = (long)n * 64;
    long stride = (long)gridDim.x * 256;
    for (int q = 0; q < 4; ++q) {
        bf16* X = Xs[q];
        int cbase = q * 256;
        for (long i = (long)blockIdx.x * 256 + tid; i < per; i += stride) {
            bf16x4 v = ((const bf16x4*)X)[i];
            int c4 = cbase + (int)(i & 63) * 4;
            float r0 = fmaf((float)v[0], aL[c4 + 0], bL[c4 + 0]); r0 = r0 > 0.f ? r0 : SLOPEV * r0;
            float r1 = fmaf((float)v[1], aL[c4 + 1], bL[c4 + 1]); r1 = r1 > 0.f ? r1 : SLOPEV * r1;
            float r2 = fmaf((float)v[2], aL[c4 + 2], bL[c4 + 2]); r2 = r2 > 0.f ? r2 : SLOPEV * r2;
            float r3 = fmaf((float)v[3], aL[c4 + 3], bL[c4 + 3]); r3 = r3 > 0.f ? r3 : SLOPEV * r3;
            bf16x4 o; o[0] = (bf16)r0; o[1] = (bf16)r1; o[2] = (bf16)r2; o[3] = (bf16)r3;
            ((bf16x4*)X)[i] = o;
        }
    }
}

// ================= host =================
struct GemmArgs {
    const bf16 *A0, *A1, *A2, *A3; int nseg, segK;
    const bf16* Wt; const float* bias; const bf16* addb;
    void *o0, *o1, *o2, *o3; int ldo, M, n_store;
    float* part; int n_stats;
};

static void gemm(hipStream_t st, const GemmArgs& a, int GY, bool store_bf16, bool stats)
{
    dim3 g(a.M / 64, GY), b(256);
    if (store_bf16) {
        if (stats)
            gemm_bt_k<true, true><<<g, b, 0, st>>>(a.A0, a.A1, a.A2, a.A3, a.nseg, a.segK,
                a.Wt, a.bias, a.addb, a.o0, a.o1, a.o2, a.o3, a.ldo, a.n_store,
                a.part, a.n_stats);
        else
            gemm_bt_k<true, false><<<g, b, 0, st>>>(a.A0, a.A1, a.A2, a.A3, a.nseg, a.segK,
                a.Wt, a.bias, a.addb, a.o0, a.o1, a.o2, a.o3, a.ldo, a.n_store,
                a.part, a.n_stats);
    } else {
        gemm_bt_k<false, false><<<g, b, 0, st>>>(a.A0, a.A1, a.A2, a.A3, a.nseg, a.segK,
            a.Wt, a.bias, a.addb, a.o0, a.o1, a.o2, a.o3, a.ldo, a.n_store,
            a.part, a.n_stats);
    }
}

extern "C" void kernel_launch(void* const* d_in, const int* in_sizes, int n_in,
                              void* d_out, int out_size, void* d_ws, size_t ws_size,
                              hipStream_t stream)
{
    const float* x       = (const float*)d_in[0];
    const int*   ei      = (const int*)d_in[1];
    const float* ew      = (const float*)d_in[2];
    const float* W_emb   = (const float*)d_in[3];
    const float* b_emb   = (const float*)d_in[4];
    const float* conv0_W = (const float*)d_in[5];
    const float* conv0_b = (const float*)d_in[6];
    const float* norm_g  = (const float*)d_in[7];
    const float* norm_b  = (const float*)d_in[8];
    const float* conv_W  = (const float*)d_in[9];
    const float* conv_b  = (const float*)d_in[10];
    const float* mlp_W1  = (const float*)d_in[11];
    const float* mlp_b1  = (const float*)d_in[12];
    const float* mlp_g   = (const float*)d_in[13];
    const float* mlp_bb  = (const float*)d_in[14];
    const float* mlp_W2  = (const float*)d_in[15];
    const float* mlp_b2  = (const float*)d_in[16];
    const float* W_out   = (const float*)d_in[17];
    const float* b_out   = (const float*)d_in[18];

    const int N = in_sizes[0] / 128;          // 50000
    const int E = in_sizes[2];                // 800000
    const int* srcI = ei;
    const int* dstI = ei + E;
    const int N_pad = ((N + 127) / 128) * 128;
    const int GY = N_pad / 128;
    const int NB = (N + 255) / 256;           // scan blocks (<=256)

    const size_t NHp = (size_t)N_pad * HDIM;
    bf16* xb = (bf16*)d_ws;                      // N_pad x 128
    bf16* hb = xb + (size_t)N_pad * 128;
    bf16* cb = hb + NHp;
    bf16* p1 = cb + NHp;
    bf16* p2 = p1 + NHp;
    bf16* e1 = p2 + NHp;                         // doubles as zb
    bf16* e2 = e1 + NHp;
    bf16* wa = e2 + NHp;                         // weight arena
    bf16* Wt_emb   = wa;
    bf16* Wt_conv0 = wa + 32768;
    bf16* Wt_conv  = wa + 229376;
    bf16* Wt_mlp1  = wa + 819200;
    bf16* Wt_mlp2  = wa + 1605632;
    bf16* Wt_out   = wa + 2392064;
    float* cf_h   = (float*)(wa + 2424832);      // 512 coeffs (h BN)
    float* cf_m   = cf_h + 512;                  // 2048 coeffs (mlp BN)
    float* partb  = cf_m + 2048;                 // 2*GY*1024 floats max
    int*   rowptr = (int*)(partb + 2 * (size_t)GY * 1024);
    int*   wp     = rowptr + (N + 1);
    int*   col    = wp + N;
    float* wgt    = (float*)(col + E);
    int*   bsum   = (int*)(wgt + E);             // 256
    int*   boff   = bsum + 256;                  // 256

    const float invn = 1.0f / (float)N;
    dim3 pg((N + 7) / 8), pb(256);

    // ---- CSR build (parallel scan) ----
    hipMemsetAsync(wp, 0, (size_t)N * 4, stream);
    deg_k<<<dim3((E + 255) / 256), dim3(256), 0, stream>>>(dstI, wp, E);
    blocksum_k<<<dim3(NB), dim3(256), 0, stream>>>(wp, bsum, N);
    topscan_k<<<dim3(1), dim3(256), 0, stream>>>(bsum, boff, NB);
    scatterscan_k<<<dim3(NB), dim3(256), 0, stream>>>(wp, boff, rowptr, N);
    reorder_k<<<dim3((E + 255) / 256), dim3(256), 0, stream>>>(srcI, dstI, ew, wp, col, wgt, E);

    // ---- convert inputs/weights ----
    cvt_bf_k<<<dim3((N * 32 + 255) / 256), dim3(256), 0, stream>>>(x, xb, (long)N * 32);
    transpose_cvt_k<<<dim3(8, 4, 1), dim3(256), 0, stream>>>(W_emb, Wt_emb, 128, 256, 1);
    transpose_cvt_k<<<dim3(8, 8, 3), dim3(256), 0, stream>>>(conv0_W, Wt_conv0, 256, 256, 3);
    transpose_cvt_k<<<dim3(8, 8, 9), dim3(256), 0, stream>>>(conv_W, Wt_conv, 256, 256, 3);
    transpose_cvt_k<<<dim3(32, 8, 3), dim3(256), 0, stream>>>(mlp_W1, Wt_mlp1, 256, 1024, 1);
    transpose_cvt_k<<<dim3(8, 32, 3), dim3(256), 0, stream>>>(mlp_W2, Wt_mlp2, 1024, 256, 1);
    transpose_cvt_k<<<dim3(4, 8, 1), dim3(256), 0, stream>>>(W_out, Wt_out, 256, 128, 1);

    // ---- embed: cb = bf16(x @ W_emb + b_emb) ----
    {
        GemmArgs a{xb, xb, xb, xb, 1, 128, Wt_emb, b_emb, nullptr,
                   cb, cb, cb, cb, HDIM, 256, N_pad, nullptr, 0};
        gemm(stream, a, GY, true, false);
    }

    // ---- conv0: hb = [cb | A.cb | A^2.cb] @ Wt_conv0 + b ; partials -> cf_h ----
    spmm_pull_k<<<pg, pb, 0, stream>>>(cb, rowptr, col, wgt, p1, N);
    spmm_pull_k<<<pg, pb, 0, stream>>>(p1, rowptr, col, wgt, p2, N);
    {
        GemmArgs a{cb, p1, p2, p2, 3, 256, Wt_conv0, conv0_b, nullptr,
                   hb, hb, hb, hb, HDIM, 256, N_pad, partb, N};
        gemm(stream, a, GY, true, true);
    }
    finalize_k<<<dim3(256), dim3(256), 0, stream>>>(partb, GY, 256, norm_g, norm_b, cf_h, invn);

    for (int l = 0; l < 3; ++l) {
        // zb(e1) = leaky(bn(hb)) using precomputed coeffs
        apply_bn_k<<<dim3(1024), dim3(256), 0, stream>>>(hb, cf_h, e1, N);

        // conv: cb = [zb | A.zb | A^2.zb] @ Wl + b
        spmm_pull_k<<<pg, pb, 0, stream>>>(e1, rowptr, col, wgt, p1, N);
        spmm_pull_k<<<pg, pb, 0, stream>>>(p1, rowptr, col, wgt, p2, N);
        {
            GemmArgs a{e1, p1, p2, p2, 3, 256, Wt_conv + (size_t)l * 196608,
                       conv_b + l * 256, nullptr, cb, cb, cb, cb, HDIM, 256, N_pad,
                       nullptr, 0};
            gemm(stream, a, GY, true, false);
        }

        // W1: {p1,p2,e1,e2} = cb @ W1 + b1 ; partials -> cf_m
        {
            GemmArgs a{cb, cb, cb, cb, 1, 256, Wt_mlp1 + (size_t)l * 262144,
                       mlp_b1 + (size_t)l * 1024, nullptr, p1, p2, e1, e2, HDIM, 1024,
                       N_pad, partb, N};
            gemm(stream, a, GY, true, true);
        }
        finalize_k<<<dim3(1024), dim3(256), 0, stream>>>(partb, GY, 1024,
                                                         mlp_g + (size_t)l * 1024,
                                                         mlp_bb + (size_t)l * 1024, cf_m, invn);

        // hidden = leaky(bn(hidden)) in-place
        apply_bn4_k<<<dim3(2048), dim3(256), 0, stream>>>(p1, p2, e1, e2, cf_m, N);

        // W2: hb += hidden @ W2 + b2 ; partials for next layer's h-BN (if any)
        {
            GemmArgs a{p1, p2, e1, e2, 4, 256, Wt_mlp2 + (size_t)l * 262144,
                       mlp_b2 + l * 256, hb, hb, hb, hb, hb, HDIM, 256, N_pad,
                       (l < 2) ? partb : nullptr, N};
            gemm(stream, a, GY, true, l < 2);
        }
        if (l < 2)
            finalize_k<<<dim3(256), dim3(256), 0, stream>>>(partb, GY, 256,
                                                            norm_g + (l + 1) * 256,
                                                            norm_b + (l + 1) * 256, cf_h, invn);
    }

    // ---- out = hb @ W_out + b_out (f32) ----
    {
        GemmArgs a{hb, hb, hb, hb, 1, 256, Wt_out, b_out, nullptr,
                   d_out, d_out, d_out, d_out, 128, 128, N, nullptr, 0};
        gemm(stream, a, GY, false, false);
    }
}

// Round 5
// 1428.312 us; speedup vs baseline: 1.0495x; 1.0495x over previous
//
#include <hip/hip_runtime.h>

#define HDIM 256
#define EPSV 1e-5f
#define SLOPEV 0.01f

typedef __bf16 bf16;
typedef bf16  bf16x8 __attribute__((ext_vector_type(8)));
typedef bf16  bf16x4 __attribute__((ext_vector_type(4)));
typedef float f32x4  __attribute__((ext_vector_type(4)));

#define GLD16(g, l) __builtin_amdgcn_global_load_lds( \
    (const __attribute__((address_space(1))) void*)(g), \
    (__attribute__((address_space(3))) void*)(l), 16, 0, 0)

// ============ MFMA GEMM: 64x128 tile (short-wide), 32x64/wave ============
// out = concat_k(A0..A_{nseg-1}) * Wt^T + bias (+addb residual).
// r4 post-mortem: A is the huge operand (25-103MB), B is tiny (<=1.5MB,
// L2-resident). Tall-skinny 128x64 doubled A's logical re-reads on M=256
// GEMMs (FETCH 15->218MB, HBM-bound). Short-wide 64x128 restores A
// amortization (gridDim.x = M/128) while keeping r4's occupancy win:
// acc = 2x4 f32x4 = 32 AGPR, ~44 VGPR, LDS 24KB.
// LDS: A [2][64][32]bf16 @0 (8KB), B [2][128][32]bf16 @8192 (16KB).
// K-loop: r1's proven issue-early stage + __syncthreads (no hand vmcnt).
// __launch_bounds__(256,5): 5 blocks/CU (reg budget 102 >= ~82 used).
template<bool STORE_BF16, bool STATS>
__global__ __launch_bounds__(256, 5)
void gemm_bt_k(const bf16* A0, const bf16* A1, const bf16* A2, const bf16* A3,
               int nseg, int segK,
               const bf16* __restrict__ Wt,
               const float* __restrict__ bias, const bf16* __restrict__ addb,
               void* out0, void* out1, void* out2, void* out3, int ldo,
               int n_store, float* part, int n_stats)
{
    __shared__ char smem[24576];

    const int tid = threadIdx.x;
    const int wave = tid >> 6, lane = tid & 63;
    const int quad = lane >> 4, l16 = lane & 15;
    const int waveM = (wave >> 1) * 32, waveN = (wave & 1) * 64;

    // T1: XCD-aware swizzle (all grids here have nwg % 8 == 0; guard anyway).
    int bid = blockIdx.y * gridDim.x + blockIdx.x;
    const int nwg = gridDim.x * gridDim.y;
    if ((nwg & 7) == 0) {
        const int cpx = nwg >> 3;
        bid = (bid & 7) * cpx + (bid >> 3);
    }
    const int bx = bid % gridDim.x, by = bid / gridDim.x;
    const int bm = by * 64, bn = bx * 128;
    const int K = nseg * segK;

    const bf16* segs[4] = {A0, A1, A2, A3};
    const int srow = tid >> 2;            // 0..63
    const int skof = (tid & 3) * 8;       // 0,8,16,24 (bf16 elems)

    f32x4 acc[2][4] = {};

    const int T = K >> 5;                 // K-steps of 32

    auto stage = [&](int s, int kt, int b) {
        const bf16* gA = segs[s] + (size_t)(bm + srow) * segK + kt + skof;
        const bf16* gB = Wt + (size_t)(bn + srow) * K + s * segK + kt + skof;
        char* lA = smem + b * 4096 + wave * 1024;
        char* lB = smem + 8192 + b * 8192 + wave * 1024;
        GLD16(gA,                  lA);             // A rows 0..63
        GLD16(gB,                  lB);             // B rows (out cols) 0..63
        GLD16(gB + (size_t)64 * K, lB + 4096);      // B rows 64..127
    };

    stage(0, 0, 0);
    __syncthreads();

    int s = 0, kt = 0;
    for (int t = 0; t < T; ++t) {
        int s2 = s, kt2 = kt + 32;
        if (kt2 == segK) { s2++; kt2 = 0; }
        if (t + 1 < T) stage(s2, kt2, (t + 1) & 1);   // issue-early prefetch

        const bf16* pa = (const bf16*)(smem + (t & 1) * 4096)
                         + (waveM + l16) * 32 + quad * 8;
        const bf16* pb = (const bf16*)(smem + 8192 + (t & 1) * 8192)
                         + (waveN + l16) * 32 + quad * 8;
        bf16x8 a0 = *(const bf16x8*)(pa);
        bf16x8 a1 = *(const bf16x8*)(pa + 16 * 32);
        bf16x8 b0 = *(const bf16x8*)(pb);
        bf16x8 b1 = *(const bf16x8*)(pb + 16 * 32);
        bf16x8 b2 = *(const bf16x8*)(pb + 32 * 32);
        bf16x8 b3 = *(const bf16x8*)(pb + 48 * 32);

        acc[0][0] = __builtin_amdgcn_mfma_f32_16x16x32_bf16(a0, b0, acc[0][0], 0, 0, 0);
        acc[0][1] = __builtin_amdgcn_mfma_f32_16x16x32_bf16(a0, b1, acc[0][1], 0, 0, 0);
        acc[0][2] = __builtin_amdgcn_mfma_f32_16x16x32_bf16(a0, b2, acc[0][2], 0, 0, 0);
        acc[0][3] = __builtin_amdgcn_mfma_f32_16x16x32_bf16(a0, b3, acc[0][3], 0, 0, 0);
        acc[1][0] = __builtin_amdgcn_mfma_f32_16x16x32_bf16(a1, b0, acc[1][0], 0, 0, 0);
        acc[1][1] = __builtin_amdgcn_mfma_f32_16x16x32_bf16(a1, b1, acc[1][1], 0, 0, 0);
        acc[1][2] = __builtin_amdgcn_mfma_f32_16x16x32_bf16(a1, b2, acc[1][2], 0, 0, 0);
        acc[1][3] = __builtin_amdgcn_mfma_f32_16x16x32_bf16(a1, b3, acc[1][3], 0, 0, 0);

        __syncthreads();
        s = s2; kt = kt2;
    }

    float bv[4];
#pragma unroll
    for (int j = 0; j < 4; ++j)
        bv[j] = bias ? bias[bn + waveN + j * 16 + l16] : 0.f;
#pragma unroll
    for (int i = 0; i < 2; ++i)
#pragma unroll
        for (int j = 0; j < 4; ++j)
#pragma unroll
            for (int r = 0; r < 4; ++r)
                acc[i][j][r] += bv[j];

    void* outs[4] = {out0, out1, out2, out3};

    if (STORE_BF16) {
        // wave-private 32x64 staging tile, row stride 72 bf16 (144B, 16B-mult)
        char* stg = smem + wave * 4608;
        float s8[8] = {}, q8[8] = {};
        const int rsel = lane >> 3, csel = lane & 7;
#pragma unroll
        for (int i = 0; i < 2; ++i)
#pragma unroll
            for (int j = 0; j < 4; ++j)
#pragma unroll
                for (int r = 0; r < 4; ++r)
                    *(bf16*)(stg + ((i * 16 + quad * 4 + r) * 72 + j * 16 + l16) * 2)
                        = (bf16)acc[i][j][r];
        // same-wave DS ops are in-order: reads below see writes above
#pragma unroll
        for (int rr = 0; rr < 4; ++rr) {
            int rl = rsel + rr * 8;
            bf16x8 v = *(const bf16x8*)(stg + (rl * 72 + csel * 8) * 2);
            int rowg = bm + waveM + rl;
            int colg = bn + waveN + csel * 8;
            int cseg = colg >> 8, cloc = colg & 255;
            size_t idx = (size_t)rowg * ldo + cloc;
            float f[8];
#pragma unroll
            for (int u = 0; u < 8; ++u) f[u] = (float)v[u];
            if (addb) {
                bf16x8 o = *(const bf16x8*)(addb + idx);
#pragma unroll
                for (int u = 0; u < 8; ++u) f[u] += (float)o[u];
            }
            bf16x8 w;
#pragma unroll
            for (int u = 0; u < 8; ++u) w[u] = (bf16)f[u];
            if (rowg < n_store) *(bf16x8*)((bf16*)outs[cseg] + idx) = w;
            if (STATS && rowg < n_stats) {
#pragma unroll
                for (int u = 0; u < 8; ++u) { s8[u] += f[u]; q8[u] += f[u] * f[u]; }
            }
        }
        if (STATS) {
            // reduce across rsel (lane bits 3..5)
#pragma unroll
            for (int m = 8; m <= 32; m <<= 1)
#pragma unroll
                for (int u = 0; u < 8; ++u) {
                    s8[u] += __shfl_xor(s8[u], m, 64);
                    q8[u] += __shfl_xor(q8[u], m, 64);
                }
            float* Ls = (float*)(smem + 18432);   // [4][64]
            float* Lq = Ls + 256;                 // [4][64]
            if (rsel == 0) {
#pragma unroll
                for (int u = 0; u < 8; ++u) {
                    Ls[wave * 64 + csel * 8 + u] = s8[u];
                    Lq[wave * 64 + csel * 8 + u] = q8[u];
                }
            }
            __syncthreads();
            if (tid < 128) {
                // cols 0..63: waves 0,2 ; cols 64..127: waves 1,3
                int hi = tid >> 6, c6 = tid & 63;
                float sv = Ls[hi * 64 + c6] + Ls[(hi + 2) * 64 + c6];
                float qv = Lq[hi * 64 + c6] + Lq[(hi + 2) * 64 + c6];
                int Mtot = gridDim.x * 128;
                int colg = bn + tid;
                part[(size_t)by * Mtot + colg] = sv;
                part[(size_t)(gridDim.y + by) * Mtot + colg] = qv;
            }
        }
    } else {
#pragma unroll
        for (int i = 0; i < 2; ++i)
#pragma unroll
            for (int j = 0; j < 4; ++j) {
                int colg = bn + waveN + j * 16 + l16;
                int cseg = colg >> 8, cloc = colg & 255;
#pragma unroll
                for (int r = 0; r < 4; ++r) {
                    int rowg = bm + waveM + i * 16 + quad * 4 + r;
                    if (rowg < n_store)
                        ((float*)outs[cseg])[(size_t)rowg * ldo + cloc] = acc[i][j][r];
                }
            }
    }
}

// ================= finalize: one block per column, tree reduce =================
__global__ __launch_bounds__(256)
void finalize_k(const float* __restrict__ part, int GY, int M,
                const float* __restrict__ g, const float* __restrict__ bb,
                float* __restrict__ coef, float invn)
{
    const int c = blockIdx.x;
    const int t = threadIdx.x;
    float s = 0.f, q = 0.f;
    const float* ps = part + c;
    const float* pq = part + (size_t)GY * M + c;
    for (int i = t; i < GY; i += 256) {
        s += ps[(size_t)i * M];
        q += pq[(size_t)i * M];
    }
#pragma unroll
    for (int m = 1; m <= 32; m <<= 1) {
        s += __shfl_xor(s, m, 64);
        q += __shfl_xor(q, m, 64);
    }
    __shared__ float Ls[4], Lq[4];
    const int w = t >> 6, l = t & 63;
    if (l == 0) { Ls[w] = s; Lq[w] = q; }
    __syncthreads();
    if (t == 0) {
        s = Ls[0] + Ls[1] + Ls[2] + Ls[3];
        q = Lq[0] + Lq[1] + Lq[2] + Lq[3];
        float mean = s * invn;
        float var  = q * invn - mean * mean;
        float a = g[c] * rsqrtf(var + EPSV);
        coef[c]     = a;
        coef[M + c] = bb[c] - mean * a;
    }
}

// ================= transpose+convert =================
__global__ __launch_bounds__(256)
void transpose_cvt_k(const float* __restrict__ src, bf16* __restrict__ dst,
                     int Kseg, int M, int G)
{
    __shared__ float t[32][33];
    const int z = blockIdx.z;
    src += (size_t)z * Kseg * M;
    const int ldd = G * Kseg;
    dst += (size_t)(z / G) * M * ldd + (size_t)(z % G) * Kseg;
    const int tM = blockIdx.x * 32, tK = blockIdx.y * 32;
    const int tx = threadIdx.x & 31, ty = threadIdx.x >> 5;
#pragma unroll
    for (int r = 0; r < 4; ++r)
        t[ty + r * 8][tx] = src[(size_t)(tK + ty + r * 8) * M + tM + tx];
    __syncthreads();
#pragma unroll
    for (int r = 0; r < 4; ++r)
        dst[(size_t)(tM + ty + r * 8) * ldd + tK + tx] = (bf16)t[tx][ty + r * 8];
}

__global__ __launch_bounds__(256)
void cvt_bf_k(const float* __restrict__ src, bf16* __restrict__ dst, long n4)
{
    long i = (long)blockIdx.x * blockDim.x + threadIdx.x;
    if (i >= n4) return;
    float4 v = ((const float4*)src)[i];
    bf16x4 o; o[0] = (bf16)v.x; o[1] = (bf16)v.y; o[2] = (bf16)v.z; o[3] = (bf16)v.w;
    ((bf16x4*)dst)[i] = o;
}

// ================= CSR build (parallel scan) =================
__global__ __launch_bounds__(256)
void deg_k(const int* __restrict__ dst, int* __restrict__ deg, int E)
{
    int e = blockIdx.x * blockDim.x + threadIdx.x;
    if (e < E) atomicAdd(&deg[dst[e]], 1);
}

__global__ __launch_bounds__(256)
void blocksum_k(const int* __restrict__ deg, int* __restrict__ bsum, int N)
{
    int i = blockIdx.x * 256 + threadIdx.x;
    int v = (i < N) ? deg[i] : 0;
#pragma unroll
    for (int m = 1; m <= 32; m <<= 1) v += __shfl_xor(v, m, 64);
    __shared__ int Ls[4];
    if ((threadIdx.x & 63) == 0) Ls[threadIdx.x >> 6] = v;
    __syncthreads();
    if (threadIdx.x == 0) bsum[blockIdx.x] = Ls[0] + Ls[1] + Ls[2] + Ls[3];
}

__global__ __launch_bounds__(256)
void topscan_k(const int* __restrict__ bsum, int* __restrict__ boff, int nb)
{
    __shared__ int s[256];
    int t = threadIdx.x;
    int v = (t < nb) ? bsum[t] : 0;
    s[t] = v;
    __syncthreads();
    for (int off = 1; off < 256; off <<= 1) {
        int u = (t >= off) ? s[t - off] : 0;
        __syncthreads();
        s[t] += u;
        __syncthreads();
    }
    if (t < nb) boff[t] = s[t] - v;   // exclusive
}

__global__ __launch_bounds__(256)
void scatterscan_k(int* __restrict__ deg_wp, const int* __restrict__ boff,
                   int* __restrict__ rowptr, int N)
{
    __shared__ int s[256];
    int t = threadIdx.x;
    int i = blockIdx.x * 256 + t;
    int v = (i < N) ? deg_wp[i] : 0;
    s[t] = v;
    __syncthreads();
    for (int off = 1; off < 256; off <<= 1) {
        int u = (t >= off) ? s[t - off] : 0;
        __syncthreads();
        s[t] += u;
        __syncthreads();
    }
    if (i < N) {
        int incl = s[t] + boff[blockIdx.x];
        rowptr[i + 1] = incl;
        deg_wp[i] = incl - v;     // exclusive -> reorder write ptr
        if (i == 0) rowptr[0] = 0;
    }
}

__global__ __launch_bounds__(256)
void reorder_k(const int* __restrict__ src, const int* __restrict__ dst,
               const float* __restrict__ ew, int* __restrict__ wp,
               int* __restrict__ col, float* __restrict__ wgt, int E)
{
    int e = blockIdx.x * blockDim.x + threadIdx.x;
    if (e >= E) return;
    int d = dst[e];
    int pos = atomicAdd(&wp[d], 1);
    col[pos] = src[e];
    wgt[pos] = ew[e];
}

// ================= pull SpMM: half-wave (32 lanes x bf16x8) per node =========
// 4-edge unroll: 4 gather loads in flight per half-wave (MLP for the
// L2/L3-latency-bound random row gathers).
__global__ __launch_bounds__(256)
void spmm_pull_k(const bf16* __restrict__ P, const int* __restrict__ rowptr,
                 const int* __restrict__ col, const float* __restrict__ wgt,
                 bf16* __restrict__ Q, int N)
{
    int node = blockIdx.x * 8 + (threadIdx.x >> 5);
    int l = threadIdx.x & 31;
    if (node >= N) return;
    int e = rowptr[node], end = rowptr[node + 1];
    float acc[8] = {};
    for (; e + 3 < end; e += 4) {
        int   s0 = col[e],     s1 = col[e + 1], s2 = col[e + 2], s3 = col[e + 3];
        float w0 = wgt[e],     w1 = wgt[e + 1], w2 = wgt[e + 2], w3 = wgt[e + 3];
        bf16x8 v0 = *(const bf16x8*)(P + (size_t)s0 * HDIM + l * 8);
        bf16x8 v1 = *(const bf16x8*)(P + (size_t)s1 * HDIM + l * 8);
        bf16x8 v2 = *(const bf16x8*)(P + (size_t)s2 * HDIM + l * 8);
        bf16x8 v3 = *(const bf16x8*)(P + (size_t)s3 * HDIM + l * 8);
#pragma unroll
        for (int u = 0; u < 8; ++u)
            acc[u] += ((float)v0[u] * w0 + (float)v1[u] * w1)
                    + ((float)v2[u] * w2 + (float)v3[u] * w3);
    }
    for (; e + 1 < end; e += 2) {
        int   s0 = col[e], s1 = col[e + 1];
        float w0 = wgt[e], w1 = wgt[e + 1];
        bf16x8 v0 = *(const bf16x8*)(P + (size_t)s0 * HDIM + l * 8);
        bf16x8 v1 = *(const bf16x8*)(P + (size_t)s1 * HDIM + l * 8);
#pragma unroll
        for (int u = 0; u < 8; ++u)
            acc[u] += (float)v0[u] * w0 + (float)v1[u] * w1;
    }
    if (e < end) {
        int s0 = col[e]; float w0 = wgt[e];
        bf16x8 v0 = *(const bf16x8*)(P + (size_t)s0 * HDIM + l * 8);
#pragma unroll
        for (int u = 0; u < 8; ++u) acc[u] += (float)v0[u] * w0;
    }
    bf16x8 o;
#pragma unroll
    for (int u = 0; u < 8; ++u) o[u] = (bf16)acc[u];
    *(bf16x8*)(Q + (size_t)node * HDIM + l * 8) = o;
}

// ================= BN apply (coeffs precomputed) =================
__global__ __launch_bounds__(256)
void apply_bn_k(const bf16* __restrict__ X, const float* __restrict__ coef,
                bf16* __restrict__ Y, int n)
{
    __shared__ float aL[256], bL[256];
    const int tid = threadIdx.x;
    aL[tid] = coef[tid]; bL[tid] = coef[256 + tid];
    __syncthreads();
    long n4 = (long)n * 64;
    for (long i = (long)blockIdx.x * 256 + tid; i < n4; i += (long)gridDim.x * 256) {
        bf16x4 v = ((const bf16x4*)X)[i];
        int c4 = (int)(i & 63) * 4;
        float r0 = fmaf((float)v[0], aL[c4 + 0], bL[c4 + 0]); r0 = r0 > 0.f ? r0 : SLOPEV * r0;
        float r1 = fmaf((float)v[1], aL[c4 + 1], bL[c4 + 1]); r1 = r1 > 0.f ? r1 : SLOPEV * r1;
        float r2 = fmaf((float)v[2], aL[c4 + 2], bL[c4 + 2]); r2 = r2 > 0.f ? r2 : SLOPEV * r2;
        float r3 = fmaf((float)v[3], aL[c4 + 3], bL[c4 + 3]); r3 = r3 > 0.f ? r3 : SLOPEV * r3;
        bf16x4 o; o[0] = (bf16)r0; o[1] = (bf16)r1; o[2] = (bf16)r2; o[3] = (bf16)r3;
        ((bf16x4*)Y)[i] = o;
    }
}

__global__ __launch_bounds__(256)
void apply_bn4_k(bf16* X0, bf16* X1, bf16* X2, bf16* X3,
                 const float* __restrict__ coef, int n)
{
    __shared__ float aL[1024], bL[1024];
    const int tid = threadIdx.x;
#pragma unroll
    for (int q = 0; q < 4; ++q) {
        int c = q * 256 + tid;
        aL[c] = coef[c]; bL[c] = coef[1024 + c];
    }
    __syncthreads();
    bf16* Xs[4] = {X0, X1, X2, X3};
    long per = (long)n * 64;
    long stride = (long)gridDim.x * 256;
    for (int q = 0; q < 4; ++q) {
        bf16* X = Xs[q];
        int cbase = q * 256;
        for (long i = (long)blockIdx.x * 256 + tid; i < per; i += stride) {
            bf16x4 v = ((const bf16x4*)X)[i];
            int c4 = cbase + (int)(i & 63) * 4;
            float r0 = fmaf((float)v[0], aL[c4 + 0], bL[c4 + 0]); r0 = r0 > 0.f ? r0 : SLOPEV * r0;
            float r1 = fmaf((float)v[1], aL[c4 + 1], bL[c4 + 1]); r1 = r1 > 0.f ? r1 : SLOPEV * r1;
            float r2 = fmaf((float)v[2], aL[c4 + 2], bL[c4 + 2]); r2 = r2 > 0.f ? r2 : SLOPEV * r2;
            float r3 = fmaf((float)v[3], aL[c4 + 3], bL[c4 + 3]); r3 = r3 > 0.f ? r3 : SLOPEV * r3;
            bf16x4 o; o[0] = (bf16)r0; o[1] = (bf16)r1; o[2] = (bf16)r2; o[3] = (bf16)r3;
            ((bf16x4*)X)[i] = o;
        }
    }
}

// ================= host =================
struct GemmArgs {
    const bf16 *A0, *A1, *A2, *A3; int nseg, segK;
    const bf16* Wt; const float* bias; const bf16* addb;
    void *o0, *o1, *o2, *o3; int ldo, M, n_store;
    float* part; int n_stats;
};

static void gemm(hipStream_t st, const GemmArgs& a, int GYr, bool store_bf16, bool stats)
{
    dim3 g(a.M / 128, GYr), b(256);
    if (store_bf16) {
        if (stats)
            gemm_bt_k<true, true><<<g, b, 0, st>>>(a.A0, a.A1, a.A2, a.A3, a.nseg, a.segK,
                a.Wt, a.bias, a.addb, a.o0, a.o1, a.o2, a.o3, a.ldo, a.n_store,
                a.part, a.n_stats);
        else
            gemm_bt_k<true, false><<<g, b, 0, st>>>(a.A0, a.A1, a.A2, a.A3, a.nseg, a.segK,
                a.Wt, a.bias, a.addb, a.o0, a.o1, a.o2, a.o3, a.ldo, a.n_store,
                a.part, a.n_stats);
    } else {
        gemm_bt_k<false, false><<<g, b, 0, st>>>(a.A0, a.A1, a.A2, a.A3, a.nseg, a.segK,
            a.Wt, a.bias, a.addb, a.o0, a.o1, a.o2, a.o3, a.ldo, a.n_store,
            a.part, a.n_stats);
    }
}

extern "C" void kernel_launch(void* const* d_in, const int* in_sizes, int n_in,
                              void* d_out, int out_size, void* d_ws, size_t ws_size,
                              hipStream_t stream)
{
    const float* x       = (const float*)d_in[0];
    const int*   ei      = (const int*)d_in[1];
    const float* ew      = (const float*)d_in[2];
    const float* W_emb   = (const float*)d_in[3];
    const float* b_emb   = (const float*)d_in[4];
    const float* conv0_W = (const float*)d_in[5];
    const float* conv0_b = (const float*)d_in[6];
    const float* norm_g  = (const float*)d_in[7];
    const float* norm_b  = (const float*)d_in[8];
    const float* conv_W  = (const float*)d_in[9];
    const float* conv_b  = (const float*)d_in[10];
    const float* mlp_W1  = (const float*)d_in[11];
    const float* mlp_b1  = (const float*)d_in[12];
    const float* mlp_g   = (const float*)d_in[13];
    const float* mlp_bb  = (const float*)d_in[14];
    const float* mlp_W2  = (const float*)d_in[15];
    const float* mlp_b2  = (const float*)d_in[16];
    const float* W_out   = (const float*)d_in[17];
    const float* b_out   = (const float*)d_in[18];

    const int N = in_sizes[0] / 128;          // 50000
    const int E = in_sizes[2];                // 800000
    const int* srcI = ei;
    const int* dstI = ei + E;
    const int N_pad = ((N + 127) / 128) * 128;
    const int GYr = N_pad / 64;               // 64-row blocks (784)
    const int NB = (N + 255) / 256;           // scan blocks (<=256)

    const size_t NHp = (size_t)N_pad * HDIM;
    bf16* xb = (bf16*)d_ws;                      // N_pad x 128
    bf16* hb = xb + (size_t)N_pad * 128;
    bf16* cb = hb + NHp;
    bf16* p1 = cb + NHp;
    bf16* p2 = p1 + NHp;
    bf16* e1 = p2 + NHp;                         // doubles as zb
    bf16* e2 = e1 + NHp;
    bf16* wa = e2 + NHp;                         // weight arena
    bf16* Wt_emb   = wa;
    bf16* Wt_conv0 = wa + 32768;
    bf16* Wt_conv  = wa + 229376;
    bf16* Wt_mlp1  = wa + 819200;
    bf16* Wt_mlp2  = wa + 1605632;
    bf16* Wt_out   = wa + 2392064;
    float* cf_h   = (float*)(wa + 2424832);      // 512 coeffs (h BN)
    float* cf_m   = cf_h + 512;                  // 2048 coeffs (mlp BN)
    float* partb  = cf_m + 2048;                 // 2*GYr*1024 floats max
    int*   rowptr = (int*)(partb + 2 * (size_t)GYr * 1024);
    int*   wp     = rowptr + (N + 1);
    int*   col    = wp + N;
    float* wgt    = (float*)(col + E);
    int*   bsum   = (int*)(wgt + E);             // 256
    int*   boff   = bsum + 256;                  // 256

    const float invn = 1.0f / (float)N;
    dim3 pg((N + 7) / 8), pb(256);

    // ---- CSR build (parallel scan) ----
    hipMemsetAsync(wp, 0, (size_t)N * 4, stream);
    deg_k<<<dim3((E + 255) / 256), dim3(256), 0, stream>>>(dstI, wp, E);
    blocksum_k<<<dim3(NB), dim3(256), 0, stream>>>(wp, bsum, N);
    topscan_k<<<dim3(1), dim3(256), 0, stream>>>(bsum, boff, NB);
    scatterscan_k<<<dim3(NB), dim3(256), 0, stream>>>(wp, boff, rowptr, N);
    reorder_k<<<dim3((E + 255) / 256), dim3(256), 0, stream>>>(srcI, dstI, ew, wp, col, wgt, E);

    // ---- convert inputs/weights ----
    cvt_bf_k<<<dim3((N * 32 + 255) / 256), dim3(256), 0, stream>>>(x, xb, (long)N * 32);
    transpose_cvt_k<<<dim3(8, 4, 1), dim3(256), 0, stream>>>(W_emb, Wt_emb, 128, 256, 1);
    transpose_cvt_k<<<dim3(8, 8, 3), dim3(256), 0, stream>>>(conv0_W, Wt_conv0, 256, 256, 3);
    transpose_cvt_k<<<dim3(8, 8, 9), dim3(256), 0, stream>>>(conv_W, Wt_conv, 256, 256, 3);
    transpose_cvt_k<<<dim3(32, 8, 3), dim3(256), 0, stream>>>(mlp_W1, Wt_mlp1, 256, 1024, 1);
    transpose_cvt_k<<<dim3(8, 32, 3), dim3(256), 0, stream>>>(mlp_W2, Wt_mlp2, 1024, 256, 1);
    transpose_cvt_k<<<dim3(4, 8, 1), dim3(256), 0, stream>>>(W_out, Wt_out, 256, 128, 1);

    // ---- embed: cb = bf16(x @ W_emb + b_emb) ----
    {
        GemmArgs a{xb, xb, xb, xb, 1, 128, Wt_emb, b_emb, nullptr,
                   cb, cb, cb, cb, HDIM, 256, N_pad, nullptr, 0};
        gemm(stream, a, GYr, true, false);
    }

    // ---- conv0: hb = [cb | A.cb | A^2.cb] @ Wt_conv0 + b ; partials -> cf_h ----
    spmm_pull_k<<<pg, pb, 0, stream>>>(cb, rowptr, col, wgt, p1, N);
    spmm_pull_k<<<pg, pb, 0, stream>>>(p1, rowptr, col, wgt, p2, N);
    {
        GemmArgs a{cb, p1, p2, p2, 3, 256, Wt_conv0, conv0_b, nullptr,
                   hb, hb, hb, hb, HDIM, 256, N_pad, partb, N};
        gemm(stream, a, GYr, true, true);
    }
    finalize_k<<<dim3(256), dim3(256), 0, stream>>>(partb, GYr, 256, norm_g, norm_b, cf_h, invn);

    for (int l = 0; l < 3; ++l) {
        // zb(e1) = leaky(bn(hb)) using precomputed coeffs
        apply_bn_k<<<dim3(1024), dim3(256), 0, stream>>>(hb, cf_h, e1, N);

        // conv: cb = [zb | A.zb | A^2.zb] @ Wl + b
        spmm_pull_k<<<pg, pb, 0, stream>>>(e1, rowptr, col, wgt, p1, N);
        spmm_pull_k<<<pg, pb, 0, stream>>>(p1, rowptr, col, wgt, p2, N);
        {
            GemmArgs a{e1, p1, p2, p2, 3, 256, Wt_conv + (size_t)l * 196608,
                       conv_b + l * 256, nullptr, cb, cb, cb, cb, HDIM, 256, N_pad,
                       nullptr, 0};
            gemm(stream, a, GYr, true, false);
        }

        // W1: {p1,p2,e1,e2} = cb @ W1 + b1 ; partials -> cf_m
        {
            GemmArgs a{cb, cb, cb, cb, 1, 256, Wt_mlp1 + (size_t)l * 262144,
                       mlp_b1 + (size_t)l * 1024, nullptr, p1, p2, e1, e2, HDIM, 1024,
                       N_pad, partb, N};
            gemm(stream, a, GYr, true, true);
        }
        finalize_k<<<dim3(1024), dim3(256), 0, stream>>>(partb, GYr, 1024,
                                                         mlp_g + (size_t)l * 1024,
                                                         mlp_bb + (size_t)l * 1024, cf_m, invn);

        // hidden = leaky(bn(hidden)) in-place
        apply_bn4_k<<<dim3(2048), dim3(256), 0, stream>>>(p1, p2, e1, e2, cf_m, N);

        // W2: hb += hidden @ W2 + b2 ; partials for next layer's h-BN (if any)
        {
            GemmArgs a{p1, p2, e1, e2, 4, 256, Wt_mlp2 + (size_t)l * 262144,
                       mlp_b2 + l * 256, hb, hb, hb, hb, hb, HDIM, 256, N_pad,
                       (l < 2) ? partb : nullptr, N};
            gemm(stream, a, GYr, true, l < 2);
        }
        if (l < 2)
            finalize_k<<<dim3(256), dim3(256), 0, stream>>>(partb, GYr, 256,
                                                            norm_g + (l + 1) * 256,
                                                            norm_b + (l + 1) * 256, cf_h, invn);
    }

    // ---- out = hb @ W_out + b_out (f32) ----
    {
        GemmArgs a{hb, hb, hb, hb, 1, 256, Wt_out, b_out, nullptr,
                   d_out, d_out, d_out, d_out, 128, 128, N, nullptr, 0};
        gemm(stream, a, GYr, false, false);
    }
}

// Round 6
// 1376.683 us; speedup vs baseline: 1.0889x; 1.0375x over previous
//
#include <hip/hip_runtime.h>

#define HDIM 256
#define EPSV 1e-5f
#define SLOPEV 0.01f

typedef __bf16 bf16;
typedef bf16  bf16x8 __attribute__((ext_vector_type(8)));
typedef bf16  bf16x4 __attribute__((ext_vector_type(4)));
typedef float f32x4  __attribute__((ext_vector_type(4)));

#define GLD16(g, l) __builtin_amdgcn_global_load_lds( \
    (const __attribute__((address_space(1))) void*)(g), \
    (__attribute__((address_space(3))) void*)(l), 16, 0, 0)

// ============ MFMA GEMM: 64x128 tile (short-wide), 32x64/wave ============
// out = concat_k(A0..A_{nseg-1}) * Wt^T + bias (+addb residual).
// FUSE_BN: A-staging goes global->reg->(a*x+b, leaky)->ds_write_b128 with
// per-column coefs fcoef[a:0..K, b:K..2K] (T14 async-split: loads issued
// before MFMA, apply+write after -> latency hides under MFMA). This lets
// W2 consume RAW hidden and deletes the 205MB/layer apply_bn4 pass.
// Numerically identical to the separate pass (f32 coef/fma, round to bf16).
// Occupancy: acc 2x4 f32x4 = 32 AGPR, LDS 24KB, launch_bounds(256,5)
// -> 5 blocks/CU (r5: measured 53% occupancy).
template<bool STORE_BF16, bool STATS, bool FUSE_BN>
__global__ __launch_bounds__(256, 5)
void gemm_bt_k(const bf16* A0, const bf16* A1, const bf16* A2, const bf16* A3,
               int nseg, int segK,
               const bf16* __restrict__ Wt,
               const float* __restrict__ bias, const bf16* __restrict__ addb,
               void* out0, void* out1, void* out2, void* out3, int ldo,
               int n_store, float* part, int n_stats,
               const float* __restrict__ fcoef)
{
    __shared__ char smem[24576];

    const int tid = threadIdx.x;
    const int wave = tid >> 6, lane = tid & 63;
    const int quad = lane >> 4, l16 = lane & 15;
    const int waveM = (wave >> 1) * 32, waveN = (wave & 1) * 64;

    // T1: XCD-aware swizzle (guarded on nwg % 8 == 0).
    int bid = blockIdx.y * gridDim.x + blockIdx.x;
    const int nwg = gridDim.x * gridDim.y;
    if ((nwg & 7) == 0) {
        const int cpx = nwg >> 3;
        bid = (bid & 7) * cpx + (bid >> 3);
    }
    const int bx = bid % gridDim.x, by = bid / gridDim.x;
    const int bm = by * 64, bn = bx * 128;
    const int K = nseg * segK;

    const bf16* segs[4] = {A0, A1, A2, A3};
    const int srow = tid >> 2;            // 0..63
    const int skof = (tid & 3) * 8;       // 0,8,16,24 (bf16 elems)

    f32x4 acc[2][4] = {};

    const int T = K >> 5;                 // K-steps of 32

    // ---- fused-path A registers (live across MFMA when FUSE_BN) ----
    bf16x8 aReg;
    float4 ca0, ca1, cd0, cd1;

    auto loadA = [&](int s, int kt) {      // issue only (no wait here)
        const bf16* gA = segs[s] + (size_t)(bm + srow) * segK + kt + skof;
        aReg = *(const bf16x8*)gA;
        int g = s * segK + kt + skof;      // global K-column
        ca0 = *(const float4*)(fcoef + g);
        ca1 = *(const float4*)(fcoef + g + 4);
        cd0 = *(const float4*)(fcoef + K + g);
        cd1 = *(const float4*)(fcoef + K + g + 4);
    };
    auto applyA = [&](int b) {             // wait, transform, ds_write
        float av[8] = {ca0.x, ca0.y, ca0.z, ca0.w, ca1.x, ca1.y, ca1.z, ca1.w};
        float dv[8] = {cd0.x, cd0.y, cd0.z, cd0.w, cd1.x, cd1.y, cd1.z, cd1.w};
        bf16x8 z;
#pragma unroll
        for (int u = 0; u < 8; ++u) {
            float f = fmaf((float)aReg[u], av[u], dv[u]);
            f = f > 0.f ? f : SLOPEV * f;
            z[u] = (bf16)f;
        }
        *(bf16x8*)(smem + b * 4096 + tid * 16) = z;
    };
    auto stageA_lds = [&](int s, int kt, int b) {
        const bf16* gA = segs[s] + (size_t)(bm + srow) * segK + kt + skof;
        GLD16(gA, smem + b * 4096 + wave * 1024);
    };
    auto stageB = [&](int s, int kt, int b) {
        const bf16* gB = Wt + (size_t)(bn + srow) * K + s * segK + kt + skof;
        char* lB = smem + 8192 + b * 8192 + wave * 1024;
        GLD16(gB,                  lB);
        GLD16(gB + (size_t)64 * K, lB + 4096);
    };

    // prologue
    if (FUSE_BN) loadA(0, 0); else stageA_lds(0, 0, 0);
    stageB(0, 0, 0);
    if (FUSE_BN) applyA(0);
    __syncthreads();

    int s = 0, kt = 0;
    for (int t = 0; t < T; ++t) {
        int s2 = s, kt2 = kt + 32;
        if (kt2 == segK) { s2++; kt2 = 0; }
        if (t + 1 < T) {                   // issue-early prefetch
            if (FUSE_BN) loadA(s2, kt2); else stageA_lds(s2, kt2, (t + 1) & 1);
            stageB(s2, kt2, (t + 1) & 1);
        }

        const bf16* pa = (const bf16*)(smem + (t & 1) * 4096)
                         + (waveM + l16) * 32 + quad * 8;
        const bf16* pb = (const bf16*)(smem + 8192 + (t & 1) * 8192)
                         + (waveN + l16) * 32 + quad * 8;
        bf16x8 a0 = *(const bf16x8*)(pa);
        bf16x8 a1 = *(const bf16x8*)(pa + 16 * 32);
        bf16x8 b0 = *(const bf16x8*)(pb);
        bf16x8 b1 = *(const bf16x8*)(pb + 16 * 32);
        bf16x8 b2 = *(const bf16x8*)(pb + 32 * 32);
        bf16x8 b3 = *(const bf16x8*)(pb + 48 * 32);

        acc[0][0] = __builtin_amdgcn_mfma_f32_16x16x32_bf16(a0, b0, acc[0][0], 0, 0, 0);
        acc[0][1] = __builtin_amdgcn_mfma_f32_16x16x32_bf16(a0, b1, acc[0][1], 0, 0, 0);
        acc[0][2] = __builtin_amdgcn_mfma_f32_16x16x32_bf16(a0, b2, acc[0][2], 0, 0, 0);
        acc[0][3] = __builtin_amdgcn_mfma_f32_16x16x32_bf16(a0, b3, acc[0][3], 0, 0, 0);
        acc[1][0] = __builtin_amdgcn_mfma_f32_16x16x32_bf16(a1, b0, acc[1][0], 0, 0, 0);
        acc[1][1] = __builtin_amdgcn_mfma_f32_16x16x32_bf16(a1, b1, acc[1][1], 0, 0, 0);
        acc[1][2] = __builtin_amdgcn_mfma_f32_16x16x32_bf16(a1, b2, acc[1][2], 0, 0, 0);
        acc[1][3] = __builtin_amdgcn_mfma_f32_16x16x32_bf16(a1, b3, acc[1][3], 0, 0, 0);

        if (FUSE_BN && t + 1 < T) applyA((t + 1) & 1);  // vmcnt hides under MFMA
        __syncthreads();
        s = s2; kt = kt2;
    }

    float bv[4];
#pragma unroll
    for (int j = 0; j < 4; ++j)
        bv[j] = bias ? bias[bn + waveN + j * 16 + l16] : 0.f;
#pragma unroll
    for (int i = 0; i < 2; ++i)
#pragma unroll
        for (int j = 0; j < 4; ++j)
#pragma unroll
            for (int r = 0; r < 4; ++r)
                acc[i][j][r] += bv[j];

    void* outs[4] = {out0, out1, out2, out3};

    if (STORE_BF16) {
        // wave-private 32x64 staging tile, row stride 72 bf16 (144B, 16B-mult)
        char* stg = smem + wave * 4608;
        float s8[8] = {}, q8[8] = {};
        const int rsel = lane >> 3, csel = lane & 7;
#pragma unroll
        for (int i = 0; i < 2; ++i)
#pragma unroll
            for (int j = 0; j < 4; ++j)
#pragma unroll
                for (int r = 0; r < 4; ++r)
                    *(bf16*)(stg + ((i * 16 + quad * 4 + r) * 72 + j * 16 + l16) * 2)
                        = (bf16)acc[i][j][r];
        // same-wave DS ops are in-order: reads below see writes above
#pragma unroll
        for (int rr = 0; rr < 4; ++rr) {
            int rl = rsel + rr * 8;
            bf16x8 v = *(const bf16x8*)(stg + (rl * 72 + csel * 8) * 2);
            int rowg = bm + waveM + rl;
            int colg = bn + waveN + csel * 8;
            int cseg = colg >> 8, cloc = colg & 255;
            size_t idx = (size_t)rowg * ldo + cloc;
            float f[8];
#pragma unroll
            for (int u = 0; u < 8; ++u) f[u] = (float)v[u];
            if (addb) {
                bf16x8 o = *(const bf16x8*)(addb + idx);
#pragma unroll
                for (int u = 0; u < 8; ++u) f[u] += (float)o[u];
            }
            bf16x8 w;
#pragma unroll
            for (int u = 0; u < 8; ++u) w[u] = (bf16)f[u];
            if (rowg < n_store) *(bf16x8*)((bf16*)outs[cseg] + idx) = w;
            if (STATS && rowg < n_stats) {
#pragma unroll
                for (int u = 0; u < 8; ++u) { s8[u] += f[u]; q8[u] += f[u] * f[u]; }
            }
        }
        if (STATS) {
            // reduce across rsel (lane bits 3..5)
#pragma unroll
            for (int m = 8; m <= 32; m <<= 1)
#pragma unroll
                for (int u = 0; u < 8; ++u) {
                    s8[u] += __shfl_xor(s8[u], m, 64);
                    q8[u] += __shfl_xor(q8[u], m, 64);
                }
            float* Ls = (float*)(smem + 18432);   // [4][64]
            float* Lq = Ls + 256;                 // [4][64]
            if (rsel == 0) {
#pragma unroll
                for (int u = 0; u < 8; ++u) {
                    Ls[wave * 64 + csel * 8 + u] = s8[u];
                    Lq[wave * 64 + csel * 8 + u] = q8[u];
                }
            }
            __syncthreads();
            if (tid < 128) {
                // cols 0..63: waves 0,2 ; cols 64..127: waves 1,3
                int hi = tid >> 6, c6 = tid & 63;
                float sv = Ls[hi * 64 + c6] + Ls[(hi + 2) * 64 + c6];
                float qv = Lq[hi * 64 + c6] + Lq[(hi + 2) * 64 + c6];
                int Mtot = gridDim.x * 128;
                int colg = bn + tid;
                part[(size_t)by * Mtot + colg] = sv;
                part[(size_t)(gridDim.y + by) * Mtot + colg] = qv;
            }
        }
    } else {
#pragma unroll
        for (int i = 0; i < 2; ++i)
#pragma unroll
            for (int j = 0; j < 4; ++j) {
                int colg = bn + waveN + j * 16 + l16;
                int cseg = colg >> 8, cloc = colg & 255;
#pragma unroll
                for (int r = 0; r < 4; ++r) {
                    int rowg = bm + waveM + i * 16 + quad * 4 + r;
                    if (rowg < n_store)
                        ((float*)outs[cseg])[(size_t)rowg * ldo + cloc] = acc[i][j][r];
                }
            }
    }
}

// ================= finalize: one block per column, tree reduce =================
__global__ __launch_bounds__(256)
void finalize_k(const float* __restrict__ part, int GY, int M,
                const float* __restrict__ g, const float* __restrict__ bb,
                float* __restrict__ coef, float invn)
{
    const int c = blockIdx.x;
    const int t = threadIdx.x;
    float s = 0.f, q = 0.f;
    const float* ps = part + c;
    const float* pq = part + (size_t)GY * M + c;
    for (int i = t; i < GY; i += 256) {
        s += ps[(size_t)i * M];
        q += pq[(size_t)i * M];
    }
#pragma unroll
    for (int m = 1; m <= 32; m <<= 1) {
        s += __shfl_xor(s, m, 64);
        q += __shfl_xor(q, m, 64);
    }
    __shared__ float Ls[4], Lq[4];
    const int w = t >> 6, l = t & 63;
    if (l == 0) { Ls[w] = s; Lq[w] = q; }
    __syncthreads();
    if (t == 0) {
        s = Ls[0] + Ls[1] + Ls[2] + Ls[3];
        q = Lq[0] + Lq[1] + Lq[2] + Lq[3];
        float mean = s * invn;
        float var  = q * invn - mean * mean;
        float a = g[c] * rsqrtf(var + EPSV);
        coef[c]     = a;
        coef[M + c] = bb[c] - mean * a;
    }
}

// ================= transpose+convert =================
__global__ __launch_bounds__(256)
void transpose_cvt_k(const float* __restrict__ src, bf16* __restrict__ dst,
                     int Kseg, int M, int G)
{
    __shared__ float t[32][33];
    const int z = blockIdx.z;
    src += (size_t)z * Kseg * M;
    const int ldd = G * Kseg;
    dst += (size_t)(z / G) * M * ldd + (size_t)(z % G) * Kseg;
    const int tM = blockIdx.x * 32, tK = blockIdx.y * 32;
    const int tx = threadIdx.x & 31, ty = threadIdx.x >> 5;
#pragma unroll
    for (int r = 0; r < 4; ++r)
        t[ty + r * 8][tx] = src[(size_t)(tK + ty + r * 8) * M + tM + tx];
    __syncthreads();
#pragma unroll
    for (int r = 0; r < 4; ++r)
        dst[(size_t)(tM + ty + r * 8) * ldd + tK + tx] = (bf16)t[tx][ty + r * 8];
}

__global__ __launch_bounds__(256)
void cvt_bf_k(const float* __restrict__ src, bf16* __restrict__ dst, long n4)
{
    long i = (long)blockIdx.x * blockDim.x + threadIdx.x;
    if (i >= n4) return;
    float4 v = ((const float4*)src)[i];
    bf16x4 o; o[0] = (bf16)v.x; o[1] = (bf16)v.y; o[2] = (bf16)v.z; o[3] = (bf16)v.w;
    ((bf16x4*)dst)[i] = o;
}

// ================= CSR build (parallel scan) =================
__global__ __launch_bounds__(256)
void deg_k(const int* __restrict__ dst, int* __restrict__ deg, int E)
{
    int e = blockIdx.x * blockDim.x + threadIdx.x;
    if (e < E) atomicAdd(&deg[dst[e]], 1);
}

__global__ __launch_bounds__(256)
void blocksum_k(const int* __restrict__ deg, int* __restrict__ bsum, int N)
{
    int i = blockIdx.x * 256 + threadIdx.x;
    int v = (i < N) ? deg[i] : 0;
#pragma unroll
    for (int m = 1; m <= 32; m <<= 1) v += __shfl_xor(v, m, 64);
    __shared__ int Ls[4];
    if ((threadIdx.x & 63) == 0) Ls[threadIdx.x >> 6] = v;
    __syncthreads();
    if (threadIdx.x == 0) bsum[blockIdx.x] = Ls[0] + Ls[1] + Ls[2] + Ls[3];
}

__global__ __launch_bounds__(256)
void topscan_k(const int* __restrict__ bsum, int* __restrict__ boff, int nb)
{
    __shared__ int s[256];
    int t = threadIdx.x;
    int v = (t < nb) ? bsum[t] : 0;
    s[t] = v;
    __syncthreads();
    for (int off = 1; off < 256; off <<= 1) {
        int u = (t >= off) ? s[t - off] : 0;
        __syncthreads();
        s[t] += u;
        __syncthreads();
    }
    if (t < nb) boff[t] = s[t] - v;   // exclusive
}

__global__ __launch_bounds__(256)
void scatterscan_k(int* __restrict__ deg_wp, const int* __restrict__ boff,
                   int* __restrict__ rowptr, int N)
{
    __shared__ int s[256];
    int t = threadIdx.x;
    int i = blockIdx.x * 256 + t;
    int v = (i < N) ? deg_wp[i] : 0;
    s[t] = v;
    __syncthreads();
    for (int off = 1; off < 256; off <<= 1) {
        int u = (t >= off) ? s[t - off] : 0;
        __syncthreads();
        s[t] += u;
        __syncthreads();
    }
    if (i < N) {
        int incl = s[t] + boff[blockIdx.x];
        rowptr[i + 1] = incl;
        deg_wp[i] = incl - v;     // exclusive -> reorder write ptr
        if (i == 0) rowptr[0] = 0;
    }
}

__global__ __launch_bounds__(256)
void reorder_k(const int* __restrict__ src, const int* __restrict__ dst,
               const float* __restrict__ ew, int* __restrict__ wp,
               int* __restrict__ col, float* __restrict__ wgt, int E)
{
    int e = blockIdx.x * blockDim.x + threadIdx.x;
    if (e >= E) return;
    int d = dst[e];
    int pos = atomicAdd(&wp[d], 1);
    col[pos] = src[e];
    wgt[pos] = ew[e];
}

// ================= pull SpMM: half-wave (32 lanes x bf16x8) per node =========
__global__ __launch_bounds__(256)
void spmm_pull_k(const bf16* __restrict__ P, const int* __restrict__ rowptr,
                 const int* __restrict__ col, const float* __restrict__ wgt,
                 bf16* __restrict__ Q, int N)
{
    int node = blockIdx.x * 8 + (threadIdx.x >> 5);
    int l = threadIdx.x & 31;
    if (node >= N) return;
    int e = rowptr[node], end = rowptr[node + 1];
    float acc[8] = {};
    for (; e + 3 < end; e += 4) {
        int   s0 = col[e],     s1 = col[e + 1], s2 = col[e + 2], s3 = col[e + 3];
        float w0 = wgt[e],     w1 = wgt[e + 1], w2 = wgt[e + 2], w3 = wgt[e + 3];
        bf16x8 v0 = *(const bf16x8*)(P + (size_t)s0 * HDIM + l * 8);
        bf16x8 v1 = *(const bf16x8*)(P + (size_t)s1 * HDIM + l * 8);
        bf16x8 v2 = *(const bf16x8*)(P + (size_t)s2 * HDIM + l * 8);
        bf16x8 v3 = *(const bf16x8*)(P + (size_t)s3 * HDIM + l * 8);
#pragma unroll
        for (int u = 0; u < 8; ++u)
            acc[u] += ((float)v0[u] * w0 + (float)v1[u] * w1)
                    + ((float)v2[u] * w2 + (float)v3[u] * w3);
    }
    for (; e + 1 < end; e += 2) {
        int   s0 = col[e], s1 = col[e + 1];
        float w0 = wgt[e], w1 = wgt[e + 1];
        bf16x8 v0 = *(const bf16x8*)(P + (size_t)s0 * HDIM + l * 8);
        bf16x8 v1 = *(const bf16x8*)(P + (size_t)s1 * HDIM + l * 8);
#pragma unroll
        for (int u = 0; u < 8; ++u)
            acc[u] += (float)v0[u] * w0 + (float)v1[u] * w1;
    }
    if (e < end) {
        int s0 = col[e]; float w0 = wgt[e];
        bf16x8 v0 = *(const bf16x8*)(P + (size_t)s0 * HDIM + l * 8);
#pragma unroll
        for (int u = 0; u < 8; ++u) acc[u] += (float)v0[u] * w0;
    }
    bf16x8 o;
#pragma unroll
    for (int u = 0; u < 8; ++u) o[u] = (bf16)acc[u];
    *(bf16x8*)(Q + (size_t)node * HDIM + l * 8) = o;
}

// ================= BN apply (coeffs precomputed) =================
__global__ __launch_bounds__(256)
void apply_bn_k(const bf16* __restrict__ X, const float* __restrict__ coef,
                bf16* __restrict__ Y, int n)
{
    __shared__ float aL[256], bL[256];
    const int tid = threadIdx.x;
    aL[tid] = coef[tid]; bL[tid] = coef[256 + tid];
    __syncthreads();
    long n4 = (long)n * 64;
    for (long i = (long)blockIdx.x * 256 + tid; i < n4; i += (long)gridDim.x * 256) {
        bf16x4 v = ((const bf16x4*)X)[i];
        int c4 = (int)(i & 63) * 4;
        float r0 = fmaf((float)v[0], aL[c4 + 0], bL[c4 + 0]); r0 = r0 > 0.f ? r0 : SLOPEV * r0;
        float r1 = fmaf((float)v[1], aL[c4 + 1], bL[c4 + 1]); r1 = r1 > 0.f ? r1 : SLOPEV * r1;
        float r2 = fmaf((float)v[2], aL[c4 + 2], bL[c4 + 2]); r2 = r2 > 0.f ? r2 : SLOPEV * r2;
        float r3 = fmaf((float)v[3], aL[c4 + 3], bL[c4 + 3]); r3 = r3 > 0.f ? r3 : SLOPEV * r3;
        bf16x4 o; o[0] = (bf16)r0; o[1] = (bf16)r1; o[2] = (bf16)r2; o[3] = (bf16)r3;
        ((bf16x4*)Y)[i] = o;
    }
}

// ================= host =================
struct GemmArgs {
    const bf16 *A0, *A1, *A2, *A3; int nseg, segK;
    const bf16* Wt; const float* bias; const bf16* addb;
    void *o0, *o1, *o2, *o3; int ldo, M, n_store;
    float* part; int n_stats;
    const float* fuse;                    // non-null: fused BN+leaky on A
};

static void gemm(hipStream_t st, const GemmArgs& a, int GYr, bool store_bf16, bool stats)
{
    dim3 g(a.M / 128, GYr), b(256);
    if (a.fuse) {
        if (stats)
            gemm_bt_k<true, true, true><<<g, b, 0, st>>>(a.A0, a.A1, a.A2, a.A3,
                a.nseg, a.segK, a.Wt, a.bias, a.addb, a.o0, a.o1, a.o2, a.o3,
                a.ldo, a.n_store, a.part, a.n_stats, a.fuse);
        else
            gemm_bt_k<true, false, true><<<g, b, 0, st>>>(a.A0, a.A1, a.A2, a.A3,
                a.nseg, a.segK, a.Wt, a.bias, a.addb, a.o0, a.o1, a.o2, a.o3,
                a.ldo, a.n_store, a.part, a.n_stats, a.fuse);
    } else if (store_bf16) {
        if (stats)
            gemm_bt_k<true, true, false><<<g, b, 0, st>>>(a.A0, a.A1, a.A2, a.A3,
                a.nseg, a.segK, a.Wt, a.bias, a.addb, a.o0, a.o1, a.o2, a.o3,
                a.ldo, a.n_store, a.part, a.n_stats, nullptr);
        else
            gemm_bt_k<true, false, false><<<g, b, 0, st>>>(a.A0, a.A1, a.A2, a.A3,
                a.nseg, a.segK, a.Wt, a.bias, a.addb, a.o0, a.o1, a.o2, a.o3,
                a.ldo, a.n_store, a.part, a.n_stats, nullptr);
    } else {
        gemm_bt_k<false, false, false><<<g, b, 0, st>>>(a.A0, a.A1, a.A2, a.A3,
            a.nseg, a.segK, a.Wt, a.bias, a.addb, a.o0, a.o1, a.o2, a.o3,
            a.ldo, a.n_store, a.part, a.n_stats, nullptr);
    }
}

extern "C" void kernel_launch(void* const* d_in, const int* in_sizes, int n_in,
                              void* d_out, int out_size, void* d_ws, size_t ws_size,
                              hipStream_t stream)
{
    const float* x       = (const float*)d_in[0];
    const int*   ei      = (const int*)d_in[1];
    const float* ew      = (const float*)d_in[2];
    const float* W_emb   = (const float*)d_in[3];
    const float* b_emb   = (const float*)d_in[4];
    const float* conv0_W = (const float*)d_in[5];
    const float* conv0_b = (const float*)d_in[6];
    const float* norm_g  = (const float*)d_in[7];
    const float* norm_b  = (const float*)d_in[8];
    const float* conv_W  = (const float*)d_in[9];
    const float* conv_b  = (const float*)d_in[10];
    const float* mlp_W1  = (const float*)d_in[11];
    const float* mlp_b1  = (const float*)d_in[12];
    const float* mlp_g   = (const float*)d_in[13];
    const float* mlp_bb  = (const float*)d_in[14];
    const float* mlp_W2  = (const float*)d_in[15];
    const float* mlp_b2  = (const float*)d_in[16];
    const float* W_out   = (const float*)d_in[17];
    const float* b_out   = (const float*)d_in[18];

    const int N = in_sizes[0] / 128;          // 50000
    const int E = in_sizes[2];                // 800000
    const int* srcI = ei;
    const int* dstI = ei + E;
    const int N_pad = ((N + 127) / 128) * 128;
    const int GYr = N_pad / 64;               // 64-row blocks
    const int NB = (N + 255) / 256;           // scan blocks (<=256)

    const size_t NHp = (size_t)N_pad * HDIM;
    bf16* xb = (bf16*)d_ws;                      // N_pad x 128
    bf16* hb = xb + (size_t)N_pad * 128;
    bf16* cb = hb + NHp;
    bf16* p1 = cb + NHp;
    bf16* p2 = p1 + NHp;
    bf16* e1 = p2 + NHp;                         // doubles as zb
    bf16* e2 = e1 + NHp;
    bf16* wa = e2 + NHp;                         // weight arena
    bf16* Wt_emb   = wa;
    bf16* Wt_conv0 = wa + 32768;
    bf16* Wt_conv  = wa + 229376;
    bf16* Wt_mlp1  = wa + 819200;
    bf16* Wt_mlp2  = wa + 1605632;
    bf16* Wt_out   = wa + 2392064;
    float* cf_h   = (float*)(wa + 2424832);      // 512 coeffs (h BN)
    float* cf_m   = cf_h + 512;                  // 2048 coeffs (mlp BN)
    float* partb  = cf_m + 2048;                 // 2*GYr*1024 floats max
    int*   rowptr = (int*)(partb + 2 * (size_t)GYr * 1024);
    int*   wp     = rowptr + (N + 1);
    int*   col    = wp + N;
    float* wgt    = (float*)(col + E);
    int*   bsum   = (int*)(wgt + E);             // 256
    int*   boff   = bsum + 256;                  // 256

    const float invn = 1.0f / (float)N;
    dim3 pg((N + 7) / 8), pb(256);

    // ---- CSR build (parallel scan) ----
    hipMemsetAsync(wp, 0, (size_t)N * 4, stream);
    deg_k<<<dim3((E + 255) / 256), dim3(256), 0, stream>>>(dstI, wp, E);
    blocksum_k<<<dim3(NB), dim3(256), 0, stream>>>(wp, bsum, N);
    topscan_k<<<dim3(1), dim3(256), 0, stream>>>(bsum, boff, NB);
    scatterscan_k<<<dim3(NB), dim3(256), 0, stream>>>(wp, boff, rowptr, N);
    reorder_k<<<dim3((E + 255) / 256), dim3(256), 0, stream>>>(srcI, dstI, ew, wp, col, wgt, E);

    // ---- convert inputs/weights ----
    cvt_bf_k<<<dim3((N * 32 + 255) / 256), dim3(256), 0, stream>>>(x, xb, (long)N * 32);
    transpose_cvt_k<<<dim3(8, 4, 1), dim3(256), 0, stream>>>(W_emb, Wt_emb, 128, 256, 1);
    transpose_cvt_k<<<dim3(8, 8, 3), dim3(256), 0, stream>>>(conv0_W, Wt_conv0, 256, 256, 3);
    transpose_cvt_k<<<dim3(8, 8, 9), dim3(256), 0, stream>>>(conv_W, Wt_conv, 256, 256, 3);
    transpose_cvt_k<<<dim3(32, 8, 3), dim3(256), 0, stream>>>(mlp_W1, Wt_mlp1, 256, 1024, 1);
    transpose_cvt_k<<<dim3(8, 32, 3), dim3(256), 0, stream>>>(mlp_W2, Wt_mlp2, 1024, 256, 1);
    transpose_cvt_k<<<dim3(4, 8, 1), dim3(256), 0, stream>>>(W_out, Wt_out, 256, 128, 1);

    // ---- embed: cb = bf16(x @ W_emb + b_emb) ----
    {
        GemmArgs a{xb, xb, xb, xb, 1, 128, Wt_emb, b_emb, nullptr,
                   cb, cb, cb, cb, HDIM, 256, N_pad, nullptr, 0, nullptr};
        gemm(stream, a, GYr, true, false);
    }

    // ---- conv0: hb = [cb | A.cb | A^2.cb] @ Wt_conv0 + b ; partials -> cf_h ----
    spmm_pull_k<<<pg, pb, 0, stream>>>(cb, rowptr, col, wgt, p1, N);
    spmm_pull_k<<<pg, pb, 0, stream>>>(p1, rowptr, col, wgt, p2, N);
    {
        GemmArgs a{cb, p1, p2, p2, 3, 256, Wt_conv0, conv0_b, nullptr,
                   hb, hb, hb, hb, HDIM, 256, N_pad, partb, N, nullptr};
        gemm(stream, a, GYr, true, true);
    }
    finalize_k<<<dim3(256), dim3(256), 0, stream>>>(partb, GYr, 256, norm_g, norm_b, cf_h, invn);

    for (int l = 0; l < 3; ++l) {
        // zb(e1) = leaky(bn(hb)) using precomputed coeffs
        apply_bn_k<<<dim3(1024), dim3(256), 0, stream>>>(hb, cf_h, e1, N);

        // conv: cb = [zb | A.zb | A^2.zb] @ Wl + b
        spmm_pull_k<<<pg, pb, 0, stream>>>(e1, rowptr, col, wgt, p1, N);
        spmm_pull_k<<<pg, pb, 0, stream>>>(p1, rowptr, col, wgt, p2, N);
        {
            GemmArgs a{e1, p1, p2, p2, 3, 256, Wt_conv + (size_t)l * 196608,
                       conv_b + l * 256, nullptr, cb, cb, cb, cb, HDIM, 256, N_pad,
                       nullptr, 0, nullptr};
            gemm(stream, a, GYr, true, false);
        }

        // W1: {p1,p2,e1,e2} = cb @ W1 + b1 (RAW hidden) ; partials -> cf_m
        {
            GemmArgs a{cb, cb, cb, cb, 1, 256, Wt_mlp1 + (size_t)l * 262144,
                       mlp_b1 + (size_t)l * 1024, nullptr, p1, p2, e1, e2, HDIM, 1024,
                       N_pad, partb, N, nullptr};
            gemm(stream, a, GYr, true, true);
        }
        finalize_k<<<dim3(1024), dim3(256), 0, stream>>>(partb, GYr, 1024,
                                                         mlp_g + (size_t)l * 1024,
                                                         mlp_bb + (size_t)l * 1024, cf_m, invn);

        // W2: hb += leaky(bn(hidden)) @ W2 + b2 — BN+leaky fused into A-staging
        // (apply_bn4 pass eliminated: saves ~205MB traffic per layer)
        {
            GemmArgs a{p1, p2, e1, e2, 4, 256, Wt_mlp2 + (size_t)l * 262144,
                       mlp_b2 + l * 256, hb, hb, hb, hb, hb, HDIM, 256, N_pad,
                       (l < 2) ? partb : nullptr, N, cf_m};
            gemm(stream, a, GYr, true, l < 2);
        }
        if (l < 2)
            finalize_k<<<dim3(256), dim3(256), 0, stream>>>(partb, GYr, 256,
                                                            norm_g + (l + 1) * 256,
                                                            norm_b + (l + 1) * 256, cf_h, invn);
    }

    // ---- out = hb @ W_out + b_out (f32) ----
    {
        GemmArgs a{hb, hb, hb, hb, 1, 256, Wt_out, b_out, nullptr,
                   d_out, d_out, d_out, d_out, 128, 128, N, nullptr, 0, nullptr};
        gemm(stream, a, GYr, false, false);
    }
}